// Round 3
// baseline (1351.012 us; speedup 1.0000x reference)
//
#include <hip/hip_runtime.h>
#include <cstdint>
#include <cstddef>

#define D_MODEL 1024
#define D_STATE 16
#define E_DIM   2048
#define SEQ     4096
#define M_ROWS  16384

typedef unsigned short u16;
typedef unsigned int   u32;
typedef __attribute__((ext_vector_type(8))) short short8;   // 8 bf16 = 4 VGPRs
typedef __attribute__((ext_vector_type(4))) float f32x4;

__device__ __forceinline__ u16 f2bf(float f) {
    u32 u = __float_as_uint(f);
    u32 r = (u + 0x7fffu + ((u >> 16) & 1u)) >> 16;   // RNE
    return (u16)r;
}
__device__ __forceinline__ float bf2f(u16 h) {
    return __uint_as_float(((u32)h) << 16);
}

// async global->LDS, 16 B per lane. LDS dest is wave-uniform base + lane*16.
__device__ __forceinline__ void gld_lds16(const void* g, void* l) {
    __builtin_amdgcn_global_load_lds(
        (__attribute__((address_space(1))) void*)(uintptr_t)g,
        (__attribute__((address_space(3))) void*)(uintptr_t)l,
        16, 0, 0);
}

// ---------------------------------------------------------------------------
// PACKED TILE LAYOUT: every GEMM operand is stored as fragment-linear 128x64
// bf16 tiles (8192 u16). Chunk c (0..1023, 16 B each): msub=c>>7,
// step=(c>>6)&1, ell=c&63 -> row = msub*16+(ell&15),
// cols = (step*4 + (ell>>4))*8 .. +7.  Staging global reads are then fully
// linear (wave reads contiguous 1 KB) AND the LDS image is fragment-ordered,
// so frag ds_read_b128 = uniform base + lane*16 (conflict-free, per R5).
// Tile (Mt, Kt) of an [M, K] operand lives at ((Mt*(K/64) + Kt) * 8192).
// ---------------------------------------------------------------------------
#define BM 128
#define BN 128
#define NBUF 4      // 4-deep LDS ring: depth-3 prefetch pipeline
#define HC_STR 17   // padded float stride for epilogue H/C tiles

// packed elementwise offset for XCp (K-dim = E_DIM = 2048, 32 k-tiles)
__device__ __forceinline__ size_t xcp_off(int m, int n) {
    int Mt = m >> 7, mr = m & 127;
    int Kt = n >> 6, nt = n & 63;
    int c16 = nt >> 3;
    int c = (mr >> 4) * 128 + (c16 >> 2) * 64 + (c16 & 3) * 16 + (mr & 15);
    return ((size_t)Mt * 32 + Kt) * 8192 + (size_t)c * 8 + (nt & 7);
}

union __align__(16) SMem {
    // 4-buffer staging ring: 4 x (16K + 16K) = 128 KB
    struct { u16 A[NBUF][BM * 64]; u16 B[NBUF][BN * 64]; } s;
    struct { float H[BM * HC_STR]; float C[BN * HC_STR]; } e;  // 8.7K + 8.7K
};

// ---------------------------------------------------------------------------
// MFMA GEMM on packed operands. C[M,N] = A[M,K] @ B[N,K]^T.
// 128x128 tile, BK=64, 4 waves (2x2 of 64x64), 4x4 16x16x32 MFMA per wave.
//
// R3: COUNTED-VMCNT DEPTH-3 PIPELINE (T4). R2 counters: 7900 cy/k-tile, 78%
// idle, ~1 block/CU -- the __syncthreads() drain (vmcnt(0)) gave each
// prefetch only one ~400cy compute phase to land, and there is no TLP to
// hide the rest. Now: 4 LDS buffers; prologue stages tiles 0..2; steady
// iteration i = { s_waitcnt vmcnt(16)  (retires stage i, keeps i+1,i+2 in
// flight -- NEVER drains to 0); s_barrier; issue stage(i+3); compute(i) }.
// Each stage has ~3 iterations of compute+issue to cover its latency.
// Tail peeled with vmcnt(8) then vmcnt(0). Buffer-reuse safety: stage(i+3)
// writes buf[(i-1)&3]; all waves finished reading it in compute(i-1) before
// barrier(i), with ds_reads retired by MFMA data-dep (compiler lgkmcnt).
//
// XCD swizzle: L%8 ~ XCD; XCD x owns m-strip, sweeps n within it.
// MODE 0: out bf16 row-major = acc + bias   (-> XP)
// MODE 1: gate: XCp <- sigmoid(acc+bias) * (H@C^T + Dp*XCp), packed in-place
// MODE 2: out fp32 row-major = acc + bias   (-> final out)
// ---------------------------------------------------------------------------
template <int MODE>
__global__ __launch_bounds__(256)
void mfma_gemm(const u16* __restrict__ Ag, const u16* __restrict__ Bg,
               int K, int Nst,
               const float* __restrict__ bias,
               u16* __restrict__ outb, float* __restrict__ outf,
               const float* __restrict__ Hm, const float* __restrict__ Cm,
               const float* __restrict__ Dp, u16* __restrict__ XCp)
{
    __shared__ SMem sm;
    const int t     = threadIdx.x;
    const int lane  = t & 63;
    const int w     = t >> 6;
    const int col_l = lane & 15;
    const int quad  = lane >> 4;
    const int wm = (w & 1) * 64;
    const int wn = (w >> 1) * 64;

    // XCD-aware swizzle (block->XCD ~ L%8): XCD owns contiguous m-strip.
    const int L = blockIdx.y * gridDim.x + blockIdx.x;
    const int xcd = L & 7, g = L >> 3;
    const int ntile = g % gridDim.x;
    const int mtile = xcd * (gridDim.y >> 3) + g / gridDim.x;
    const int bm = mtile * BM;
    const int bn = ntile * BN;

    const int KT = K >> 6;
    const u16* Abase = Ag + (size_t)mtile * KT * 8192;
    const u16* Bbase = Bg + (size_t)ntile * KT * 8192;

    f32x4 acc[4][4] = {};

    // ---- stage tile j into ring buffer buf (8 async 16B-per-lane DMAs) ----
    auto stage = [&](int j, int buf) {
        const u16* at = Abase + (size_t)j * 8192;
        const u16* bt = Bbase + (size_t)j * 8192;
#pragma unroll
        for (int i = 0; i < 4; ++i)
            gld_lds16(at + (i * 256 + t) * 8, &sm.s.A[buf][(i * 256 + t) * 8]);
#pragma unroll
        for (int i = 0; i < 4; ++i)
            gld_lds16(bt + (i * 256 + t) * 8, &sm.s.B[buf][(i * 256 + t) * 8]);
    };

    // ---- compute tile from ring buffer buf ----
    auto compute = [&](int buf) {
#pragma unroll
        for (int step = 0; step < 2; ++step) {   // two K=32 MFMA steps
            short8 af[4], bfr[4];
#pragma unroll
            for (int i = 0; i < 4; ++i) {
                int msub = (w & 1) * 4 + i;
                af[i] = *(const short8*)&sm.s.A[buf][((msub * 2 + step) * 64 + lane) * 8];
            }
#pragma unroll
            for (int j = 0; j < 4; ++j) {
                int nsub = (w >> 1) * 4 + j;
                bfr[j] = *(const short8*)&sm.s.B[buf][((nsub * 2 + step) * 64 + lane) * 8];
            }
#pragma unroll
            for (int i = 0; i < 4; ++i)
#pragma unroll
                for (int j = 0; j < 4; ++j)
                    acc[i][j] = __builtin_amdgcn_mfma_f32_16x16x32_bf16(
                        af[i], bfr[j], acc[i][j], 0, 0, 0);
        }
    };

    // prologue: fill 3 pipeline slots
    stage(0, 0);
    stage(1, 1);
    stage(2, 2);

    // main loop: i = 0 .. KT-3  (always 2 stages kept in flight)
    for (int i = 0; i < KT - 2; ++i) {
        asm volatile("s_waitcnt vmcnt(16)" ::: "memory");  // stage(i) done
        __builtin_amdgcn_sched_barrier(0);
        __builtin_amdgcn_s_barrier();                      // all waves' stage(i) done
        asm volatile("" ::: "memory");
        if (i + 3 < KT) stage(i + 3, (i + 3) & 3);         // overwrite buf[(i-1)&3]
        compute(i & 3);
    }
    // peel i = KT-2: only stage(KT-1) still younger
    {
        asm volatile("s_waitcnt vmcnt(8)" ::: "memory");
        __builtin_amdgcn_sched_barrier(0);
        __builtin_amdgcn_s_barrier();
        asm volatile("" ::: "memory");
        compute((KT - 2) & 3);
    }
    // peel i = KT-1: drain
    {
        asm volatile("s_waitcnt vmcnt(0)" ::: "memory");
        __builtin_amdgcn_sched_barrier(0);
        __builtin_amdgcn_s_barrier();
        asm volatile("" ::: "memory");
        compute((KT - 1) & 3);
    }
    __syncthreads();   // all LDS reads done before epilogue reuses the union

    // C/D layout: col = lane&15, row = quad*4 + reg   [verified m89/m91]
    if (MODE == 0) {
#pragma unroll
        for (int j = 0; j < 4; ++j) {
            int n = bn + wn + j * 16 + col_l;
            float bv = bias[n];
#pragma unroll
            for (int i = 0; i < 4; ++i) {
                int mb = bm + wm + i * 16 + quad * 4;
#pragma unroll
                for (int p = 0; p < 4; ++p)
                    outb[(size_t)(mb + p) * Nst + n] = f2bf(acc[i][j][p] + bv);
            }
        }
    } else if (MODE == 1) {
        for (int idx = t; idx < BM * D_STATE; idx += 256)
            sm.e.H[(idx >> 4) * HC_STR + (idx & 15)] =
                Hm[(size_t)(bm + (idx >> 4)) * D_STATE + (idx & 15)];
        for (int idx = t; idx < BN * D_STATE; idx += 256)
            sm.e.C[(idx >> 4) * HC_STR + (idx & 15)] =
                Cm[(size_t)(bn + (idx >> 4)) * D_STATE + (idx & 15)];
        __syncthreads();
#pragma unroll
        for (int i = 0; i < 4; ++i) {
            int ml = wm + i * 16 + quad * 4;
#pragma unroll
            for (int p = 0; p < 4; ++p) {
                float hrow[D_STATE];
#pragma unroll
                for (int s = 0; s < D_STATE; ++s)
                    hrow[s] = sm.e.H[(ml + p) * HC_STR + s];
#pragma unroll
                for (int j = 0; j < 4; ++j) {
                    int nl = wn + j * 16 + col_l;
                    int n = bn + nl;
                    float z = acc[i][j][p] + bias[n];
                    float sig = 1.f / (1.f + __expf(-z));
                    float dot = 0.f;
#pragma unroll
                    for (int s = 0; s < D_STATE; ++s)
                        dot += hrow[s] * sm.e.C[nl * HC_STR + s];
                    // packed in-place RMW: read & write the SAME address
                    size_t off = xcp_off(bm + ml + p, n);
                    float xc = bf2f(XCp[off]);
                    XCp[off] = f2bf(sig * (dot + Dp[n] * xc));
                }
            }
        }
    } else {
#pragma unroll
        for (int j = 0; j < 4; ++j) {
            int n = bn + wn + j * 16 + col_l;
            float bv = bias[n];
#pragma unroll
            for (int i = 0; i < 4; ++i) {
                int mb = bm + wm + i * 16 + quad * 4;
#pragma unroll
                for (int p = 0; p < 4; ++p)
                    outf[(size_t)(mb + p) * Nst + n] = acc[i][j][p] + bv;
            }
        }
    }
}

// ---------------------------------------------------------------------------
// pack x fp32 [16384,1024] -> packed bf16 tiles (K-dim 1024, 16 k-tiles)
// ---------------------------------------------------------------------------
__global__ __launch_bounds__(256)
void pack_x_kernel(const float* __restrict__ x, u16* __restrict__ xp)
{
    const int Kt = blockIdx.x;   // 0..15
    const int Mt = blockIdx.y;   // 0..127
    const int t  = threadIdx.x;
    u16* dst = xp + ((size_t)Mt * 16 + Kt) * 8192;
#pragma unroll
    for (int i = 0; i < 4; ++i) {
        int c   = i * 256 + t;
        int ell = c & 63;
        int row = Mt * 128 + (c >> 7) * 16 + (ell & 15);
        int col = Kt * 64 + (((c >> 6) & 1) * 4 + (ell >> 4)) * 8;
        const float4* src = (const float4*)&x[(size_t)row * D_MODEL + col];
        float4 a = src[0], b = src[1];
        alignas(16) u16 o[8] = {f2bf(a.x), f2bf(a.y), f2bf(a.z), f2bf(a.w),
                                f2bf(b.x), f2bf(b.y), f2bf(b.z), f2bf(b.w)};
        *(short8*)(dst + c * 8) = *(const short8*)o;
    }
}

// ---------------------------------------------------------------------------
// pack W^T: src W [K, Wstride] fp32 (cols colOff..colOff+Nt*128) -> packed
// bf16 tiles of B = W^T [N, K].
// ---------------------------------------------------------------------------
__global__ __launch_bounds__(256)
void pack_w_kernel(const float* __restrict__ W, u16* __restrict__ out,
                   int Wstride, int colOff, int KT)
{
    const int Kt = blockIdx.x;
    const int Nt = blockIdx.y;
    const int t  = threadIdx.x;
    u16* dst = out + ((size_t)Nt * KT + Kt) * 8192;
#pragma unroll
    for (int i = 0; i < 4; ++i) {
        int c    = i * 256 + t;
        int ell  = c & 63;
        int nrow = Nt * 128 + (c >> 7) * 16 + (ell & 15);
        int kcol = Kt * 64 + (((c >> 6) & 1) * 4 + (ell >> 4)) * 8;
        alignas(16) u16 o[8];
#pragma unroll
        for (int q = 0; q < 8; ++q)
            o[q] = f2bf(W[(size_t)(kcol + q) * Wstride + colOff + nrow]);
        *(short8*)(dst + c * 8) = *(const short8*)o;
    }
}

// ---------------------------------------------------------------------------
// causal depthwise conv (taps=4): XP row-major bf16 -> XCp PACKED bf16.
// block per (k-tile, m-tile); writes are fully linear per tile.
// ---------------------------------------------------------------------------
__global__ __launch_bounds__(256)
void conv_kernel(const u16* __restrict__ XP, const float* __restrict__ conv_w,
                 const float* __restrict__ conv_b, u16* __restrict__ XCp)
{
    const int Kt = blockIdx.x;   // 0..31
    const int Mt = blockIdx.y;   // 0..127
    const int t  = threadIdx.x;
    u16* dst = XCp + ((size_t)Mt * 32 + Kt) * 8192;
#pragma unroll
    for (int i = 0; i < 4; ++i) {
        int c   = i * 256 + t;
        int ell = c & 63;
        int mr  = (c >> 7) * 16 + (ell & 15);
        int e   = Kt * 64 + (((c >> 6) & 1) * 4 + (ell >> 4)) * 8;
        int m   = Mt * 128 + mr;
        int l   = m & (SEQ - 1);
        float acc[8];
        {
            float4 c0 = *(const float4*)&conv_b[e];
            float4 c1 = *(const float4*)&conv_b[e + 4];
            acc[0] = c0.x; acc[1] = c0.y; acc[2] = c0.z; acc[3] = c0.w;
            acc[4] = c1.x; acc[5] = c1.y; acc[6] = c1.z; acc[7] = c1.w;
        }
#pragma unroll
        for (int k = 0; k < 4; ++k) {
            if (l - 3 + k >= 0) {
                const short8 xv = *(const short8*)&XP[(size_t)(m - 3 + k) * E_DIM + e];
#pragma unroll
                for (int j = 0; j < 8; ++j)
                    acc[j] += bf2f((u16)xv[j]) * conv_w[(size_t)(e + j) * 4 + k];
            }
        }
        alignas(16) u16 o[8];
#pragma unroll
        for (int j = 0; j < 8; ++j) o[j] = f2bf(acc[j]);
        *(short8*)(dst + c * 8) = *(const short8*)o;
    }
}

// ---------------------------------------------------------------------------
// U[m,s] = sum_e XCp[m,e] * A[e,s]  (fp32 acc; reads packed XCp)
// ---------------------------------------------------------------------------
__global__ __launch_bounds__(256)
void u_kernel(const u16* __restrict__ XCp, const float* __restrict__ Amat,
              float* __restrict__ U)
{
    __shared__ float part[(256 + 16) * HC_STR];
    const int m = blockIdx.x, t = threadIdx.x;
    const int Mt = m >> 7, mr = m & 127;
    const int Kt = t >> 3, c16 = t & 7;
    const int e0 = Kt * 64 + c16 * 8;
    const int c  = (mr >> 4) * 128 + (c16 >> 2) * 64 + (c16 & 3) * 16 + (mr & 15);
    const short8 xv = *(const short8*)&XCp[((size_t)Mt * 32 + Kt) * 8192 + (size_t)c * 8];

    float acc[16];
#pragma unroll
    for (int s = 0; s < 16; ++s) acc[s] = 0.f;
#pragma unroll
    for (int q = 0; q < 8; ++q) {
        float xq = bf2f((u16)xv[q]);
        const float4* ar = (const float4*)&Amat[(size_t)(e0 + q) * D_STATE];
#pragma unroll
        for (int s4 = 0; s4 < 4; ++s4) {
            float4 a = ar[s4];
            acc[s4 * 4 + 0] += xq * a.x; acc[s4 * 4 + 1] += xq * a.y;
            acc[s4 * 4 + 2] += xq * a.z; acc[s4 * 4 + 3] += xq * a.w;
        }
    }
#pragma unroll
    for (int s = 0; s < 16; ++s) part[t * HC_STR + s] = acc[s];
    __syncthreads();
    {
        int s = t & 15, grp = t >> 4;
        float sum = 0.f;
#pragma unroll
        for (int r = 0; r < 16; ++r) sum += part[(grp + r * 16) * HC_STR + s];
        part[(256 + grp) * HC_STR + s] = sum;
    }
    __syncthreads();
    if (t < 16) {
        float sum = 0.f;
#pragma unroll
        for (int g2 = 0; g2 < 16; ++g2) sum += part[(256 + g2) * HC_STR + t];
        U[(size_t)m * D_STATE + t] = sum;
    }
}

// ---------------------------------------------------------------------------
// sequential scan: h_l = tanh(U_l + h_{l-1}), 64 chains.
// Chunked by 8 with FULLY-UNROLLED static-index arrays (stay in VGPRs --
// R6's dynamic ring index spilled to scratch: 1413 us, 830 cyc/iter).
// Next chunk's 8 independent loads issue before this chunk's ~290-cycle
// dependent tanh chain, covering L2/L3 latency.
// ---------------------------------------------------------------------------
__global__ __launch_bounds__(64)
void scan_kernel(const float* __restrict__ U, float* __restrict__ H)
{
    const int t = threadIdx.x;
    const int b = t >> 4;
    const int s = t & 15;
    const float* u = U + (size_t)b * SEQ * D_STATE + s;
    float*       h = H + (size_t)b * SEQ * D_STATE + s;

    float cur[8], nxt[8];
#pragma unroll
    for (int j = 0; j < 8; ++j) cur[j] = u[(size_t)j * D_STATE];

    float hv = 0.f;
    for (int l0 = 0; l0 < SEQ; l0 += 8) {
        if (l0 + 8 < SEQ) {
#pragma unroll
            for (int j = 0; j < 8; ++j)
                nxt[j] = u[(size_t)(l0 + 8 + j) * D_STATE];
        }
#pragma unroll
        for (int j = 0; j < 8; ++j) {
            float ex = __expf(2.f * (cur[j] + hv));
            hv = 1.f - 2.f / (ex + 1.f);
            h[(size_t)(l0 + j) * D_STATE] = hv;
        }
#pragma unroll
        for (int j = 0; j < 8; ++j) cur[j] = nxt[j];
    }
}

// ---------------------------------------------------------------------------
extern "C" void kernel_launch(void* const* d_in, const int* in_sizes, int n_in,
                              void* d_out, int out_size, void* d_ws, size_t ws_size,
                              hipStream_t stream)
{
    const float* x      = (const float*)d_in[0];
    const float* W_in   = (const float*)d_in[1];
    const float* b_in   = (const float*)d_in[2];
    const float* conv_w = (const float*)d_in[3];
    const float* conv_b = (const float*)d_in[4];
    const float* Amat   = (const float*)d_in[5];
    const float* Cmat   = (const float*)d_in[6];
    const float* Dp     = (const float*)d_in[7];
    const float* W_out  = (const float*)d_in[8];
    const float* b_out  = (const float*)d_in[9];
    float* out = (float*)d_out;

    // workspace layout (115.3 MB total; 136 MB proven safe)
    char* ws = (char*)d_ws;
    u16*   xbp  = (u16*)(ws);                    // 33.55 MB packed x
    u16*   Wp0  = (u16*)(ws +  33554432);        //  4.19 MB packed W_in[:, :2048]^T
    u16*   Wp1  = (u16*)(ws +  37748736);        //  4.19 MB packed W_in[:, 2048:]^T
    u16*   Wp2  = (u16*)(ws +  41943040);        //  4.19 MB packed W_out^T
    u16*   XCp  = (u16*)(ws +  46137344);        // 67.11 MB packed x_conv
    float* U    = (float*)(ws + 113246208);      //  1.05 MB
    float* H    = (float*)(ws + 114294784);      //  1.05 MB
    u16*   XP   = (u16*)d_out;  // x_proj bf16 in d_out (67.1 MB), dead after conv

    // 1) pack inputs
    pack_x_kernel<<<dim3(16, 128), 256, 0, stream>>>(x, xbp);
    pack_w_kernel<<<dim3(16, 16), 256, 0, stream>>>(W_in, Wp0, 2 * E_DIM, 0, 16);
    pack_w_kernel<<<dim3(16, 16), 256, 0, stream>>>(W_in, Wp1, 2 * E_DIM, E_DIM, 16);
    pack_w_kernel<<<dim3(32, 8), 256, 0, stream>>>(W_out, Wp2, D_MODEL, 0, 32);

    // 2) XP = bf16(x @ W_in[:, :2048] + b_in)   (row-major, -> d_out)
    mfma_gemm<0><<<dim3(16, 128), 256, 0, stream>>>(
        xbp, Wp0, D_MODEL, E_DIM, b_in, XP, nullptr, nullptr, nullptr, nullptr, nullptr);

    // 3) XCp = packed bf16(causal_conv(XP) + conv_b)
    conv_kernel<<<dim3(32, 128), 256, 0, stream>>>(XP, conv_w, conv_b, XCp);

    // 4) U = XC @ A ; 5) scan -> H
    u_kernel<<<M_ROWS, 256, 0, stream>>>(XCp, Amat, U);
    scan_kernel<<<1, 64, 0, stream>>>(U, H);

    // 6) XCp <- sigmoid(x @ W_in[:, 2048:] + b_in[2048:]) * (H@C^T + Dp*XCp)
    mfma_gemm<1><<<dim3(16, 128), 256, 0, stream>>>(
        xbp, Wp1, D_MODEL, 0, b_in + E_DIM, nullptr, nullptr, H, Cmat, Dp, XCp);

    // 7) out = XC @ W_out + b_out   (fp32, row-major)
    mfma_gemm<2><<<dim3(8, 128), 256, 0, stream>>>(
        XCp, Wp2, E_DIM, D_MODEL, b_out, nullptr, out, nullptr, nullptr, nullptr, nullptr);
}

// Round 4
// 1276.016 us; speedup vs baseline: 1.0588x; 1.0588x over previous
//
#include <hip/hip_runtime.h>
#include <cstdint>
#include <cstddef>

#define D_MODEL 1024
#define D_STATE 16
#define E_DIM   2048
#define SEQ     4096
#define M_ROWS  16384

typedef unsigned short u16;
typedef unsigned int   u32;
typedef __attribute__((ext_vector_type(8))) short short8;   // 8 bf16 = 4 VGPRs
typedef __attribute__((ext_vector_type(4))) float f32x4;

__device__ __forceinline__ u16 f2bf(float f) {
    u32 u = __float_as_uint(f);
    u32 r = (u + 0x7fffu + ((u >> 16) & 1u)) >> 16;   // RNE
    return (u16)r;
}
__device__ __forceinline__ float bf2f(u16 h) {
    return __uint_as_float(((u32)h) << 16);
}

// ---------------------------------------------------------------------------
// PACKED TILE LAYOUT: every GEMM operand is stored as fragment-linear 128x64
// bf16 tiles (8192 u16). Chunk c (0..1023, 16 B each): msub=c>>7,
// step=(c>>6)&1, ell=c&63 -> row = msub*16+(ell&15),
// cols = (step*4 + (ell>>4))*8 .. +7.  A lane's MFMA fragment (sub, step) is
// the 16 contiguous bytes at tile_base + ((sub*2+step)*64 + lane)*8 u16 --
// so fragments are loaded DIRECTLY global->VGPR, fully coalesced (the wave
// reads a contiguous 1 KB per global_load_dwordx4).
// Tile (Mt, Kt) of an [M, K] operand lives at ((Mt*(K/64) + Kt) * 8192).
// ---------------------------------------------------------------------------
#define BM 128
#define BN 128
#define HC_STR 17   // padded float stride for epilogue H/C tiles

// packed elementwise offset for XCp (K-dim = E_DIM = 2048, 32 k-tiles)
__device__ __forceinline__ size_t xcp_off(int m, int n) {
    int Mt = m >> 7, mr = m & 127;
    int Kt = n >> 6, nt = n & 63;
    int c16 = nt >> 3;
    int c = (mr >> 4) * 128 + (c16 >> 2) * 64 + (c16 & 3) * 16 + (mr & 15);
    return ((size_t)Mt * 32 + Kt) * 8192 + (size_t)c * 8 + (nt & 7);
}

// ---------------------------------------------------------------------------
// MFMA GEMM on packed operands. C[M,N] = A[M,K] @ B[N,K]^T.
// 128x128 tile, BK=64, 4 waves (2x2 of 64x64), 4x4 16x16x32 MFMA per wave.
//
// R4: REGISTER-DIRECT K-LOOP (no LDS, no barriers, no global_load_lds).
// R0-R3 post-mortem: occupancy pinned at ~1 block/CU across LDS 32/64/128 KB
// and across 2-barrier / drain-0 dbuf / depth-3 counted-vmcnt structures
// (509/423/390 us, MfmaUtil 5-7%, ~1.3 KB/CU in flight vs ~15 KB needed).
// The barrier-lockstepped single block can never hold enough outstanding
// requests; pipeline depth was not the lever. Now each wave streams its own
// fragments global->VGPR (packed layout = fragment-linear, so every load is
// a coalesced contiguous 1 KB), ping-ponging 2 k-tiles of fragments in
// registers with static indexing. Waves are fully independent: 16 loads in
// flight/wave, ~8 waves/CU -> ~128 KB/CU MLP. Cost: A,B each read twice
// per block (2x2 wave grid) -> ~13.5 TB/s L2 demand, under the 34.5 ceiling.
//
// XCD swizzle: L%8 ~ XCD; XCD x owns m-strip, sweeps n within it.
// MODE 0: out bf16 row-major = acc + bias   (-> XP)
// MODE 1: gate: XCp <- sigmoid(acc+bias) * (H@C^T + Dp*XCp), packed in-place
// MODE 2: out fp32 row-major = acc + bias   (-> final out)
// ---------------------------------------------------------------------------
template <int MODE>
__global__ __launch_bounds__(256)
void mfma_gemm(const u16* __restrict__ Ag, const u16* __restrict__ Bg,
               int K, int Nst,
               const float* __restrict__ bias,
               u16* __restrict__ outb, float* __restrict__ outf,
               const float* __restrict__ Hm, const float* __restrict__ Cm,
               const float* __restrict__ Dp, u16* __restrict__ XCp)
{
    const int t     = threadIdx.x;
    const int lane  = t & 63;
    const int w     = t >> 6;
    const int col_l = lane & 15;
    const int quad  = lane >> 4;
    const int wm = (w & 1) * 64;
    const int wn = (w >> 1) * 64;

    // XCD-aware swizzle (block->XCD ~ L%8): XCD owns contiguous m-strip.
    const int L = blockIdx.y * gridDim.x + blockIdx.x;
    const int xcd = L & 7, g = L >> 3;
    const int ntile = g % gridDim.x;
    const int mtile = xcd * (gridDim.y >> 3) + g / gridDim.x;
    const int bm = mtile * BM;
    const int bn = ntile * BN;

    const int KT = K >> 6;
    // per-wave fragment base: frag (i, step) of k-tile kt lives at
    //   base + kt*8192 + (i*2+step)*512   (u16 units; 16 B per lane)
    const u16* aw = Ag + (size_t)mtile * KT * 8192 + (size_t)(w & 1) * 4096
                       + (size_t)lane * 8;
    const u16* bw = Bg + (size_t)ntile * KT * 8192 + (size_t)(w >> 1) * 4096
                       + (size_t)lane * 8;

    f32x4 acc[4][4] = {};

    // load the 8 fragments (4 A + 4 B) of one K=32 step into registers
    auto ldfrag = [&](short8* da, short8* db, size_t off, int step) {
#pragma unroll
        for (int i = 0; i < 4; ++i) {
            da[i] = *(const short8*)(aw + off + (size_t)((i * 2 + step) * 512));
            db[i] = *(const short8*)(bw + off + (size_t)((i * 2 + step) * 512));
        }
    };
    auto mfma16 = [&](short8* af, short8* bfr) {
#pragma unroll
        for (int i = 0; i < 4; ++i)
#pragma unroll
            for (int j = 0; j < 4; ++j)
                acc[i][j] = __builtin_amdgcn_mfma_f32_16x16x32_bf16(
                    af[i], bfr[j], acc[i][j], 0, 0, 0);
    };

    // register ping-pong: 4 fragment groups (2 k-tiles), static indexing only
    short8 A0[4], B0[4], A1[4], B1[4], A2[4], B2[4], A3[4], B3[4];
    size_t off = 0;
    ldfrag(A0, B0, off, 0);
    ldfrag(A1, B1, off, 1);
    for (int kt = 0; kt < KT; kt += 2) {
        // prefetch k-tile kt+1 while computing kt
        ldfrag(A2, B2, off + 8192, 0);
        ldfrag(A3, B3, off + 8192, 1);
        mfma16(A0, B0);
        mfma16(A1, B1);
        // prefetch k-tile kt+2 while computing kt+1
        if (kt + 2 < KT) {
            ldfrag(A0, B0, off + 16384, 0);
            ldfrag(A1, B1, off + 16384, 1);
        }
        mfma16(A2, B2);
        mfma16(A3, B3);
        off += 16384;
    }

    // C/D layout: col = lane&15, row = quad*4 + reg   [verified m89/m91]
    if (MODE == 0) {
#pragma unroll
        for (int j = 0; j < 4; ++j) {
            int n = bn + wn + j * 16 + col_l;
            float bv = bias[n];
#pragma unroll
            for (int i = 0; i < 4; ++i) {
                int mb = bm + wm + i * 16 + quad * 4;
#pragma unroll
                for (int p = 0; p < 4; ++p)
                    outb[(size_t)(mb + p) * Nst + n] = f2bf(acc[i][j][p] + bv);
            }
        }
    } else if (MODE == 1) {
        __shared__ float Hs[BM * HC_STR];
        __shared__ float Cs[BN * HC_STR];
        for (int idx = t; idx < BM * D_STATE; idx += 256)
            Hs[(idx >> 4) * HC_STR + (idx & 15)] =
                Hm[(size_t)(bm + (idx >> 4)) * D_STATE + (idx & 15)];
        for (int idx = t; idx < BN * D_STATE; idx += 256)
            Cs[(idx >> 4) * HC_STR + (idx & 15)] =
                Cm[(size_t)(bn + (idx >> 4)) * D_STATE + (idx & 15)];
        __syncthreads();
#pragma unroll
        for (int i = 0; i < 4; ++i) {
            int ml = wm + i * 16 + quad * 4;
#pragma unroll
            for (int p = 0; p < 4; ++p) {
                float hrow[D_STATE];
#pragma unroll
                for (int s = 0; s < D_STATE; ++s)
                    hrow[s] = Hs[(ml + p) * HC_STR + s];
#pragma unroll
                for (int j = 0; j < 4; ++j) {
                    int nl = wn + j * 16 + col_l;
                    int n = bn + nl;
                    float z = acc[i][j][p] + bias[n];
                    float sig = 1.f / (1.f + __expf(-z));
                    float dot = 0.f;
#pragma unroll
                    for (int s = 0; s < D_STATE; ++s)
                        dot += hrow[s] * Cs[nl * HC_STR + s];
                    // packed in-place RMW: read & write the SAME address
                    size_t offx = xcp_off(bm + ml + p, n);
                    float xc = bf2f(XCp[offx]);
                    XCp[offx] = f2bf(sig * (dot + Dp[n] * xc));
                }
            }
        }
    } else {
#pragma unroll
        for (int j = 0; j < 4; ++j) {
            int n = bn + wn + j * 16 + col_l;
            float bv = bias[n];
#pragma unroll
            for (int i = 0; i < 4; ++i) {
                int mb = bm + wm + i * 16 + quad * 4;
#pragma unroll
                for (int p = 0; p < 4; ++p)
                    outf[(size_t)(mb + p) * Nst + n] = acc[i][j][p] + bv;
            }
        }
    }
}

// ---------------------------------------------------------------------------
// pack x fp32 [16384,1024] -> packed bf16 tiles (K-dim 1024, 16 k-tiles)
// ---------------------------------------------------------------------------
__global__ __launch_bounds__(256)
void pack_x_kernel(const float* __restrict__ x, u16* __restrict__ xp)
{
    const int Kt = blockIdx.x;   // 0..15
    const int Mt = blockIdx.y;   // 0..127
    const int t  = threadIdx.x;
    u16* dst = xp + ((size_t)Mt * 16 + Kt) * 8192;
#pragma unroll
    for (int i = 0; i < 4; ++i) {
        int c   = i * 256 + t;
        int ell = c & 63;
        int row = Mt * 128 + (c >> 7) * 16 + (ell & 15);
        int col = Kt * 64 + (((c >> 6) & 1) * 4 + (ell >> 4)) * 8;
        const float4* src = (const float4*)&x[(size_t)row * D_MODEL + col];
        float4 a = src[0], b = src[1];
        alignas(16) u16 o[8] = {f2bf(a.x), f2bf(a.y), f2bf(a.z), f2bf(a.w),
                                f2bf(b.x), f2bf(b.y), f2bf(b.z), f2bf(b.w)};
        *(short8*)(dst + c * 8) = *(const short8*)o;
    }
}

// ---------------------------------------------------------------------------
// pack W^T: src W [K, Wstride] fp32 (cols colOff..colOff+Nt*128) -> packed
// bf16 tiles of B = W^T [N, K].
// ---------------------------------------------------------------------------
__global__ __launch_bounds__(256)
void pack_w_kernel(const float* __restrict__ W, u16* __restrict__ out,
                   int Wstride, int colOff, int KT)
{
    const int Kt = blockIdx.x;
    const int Nt = blockIdx.y;
    const int t  = threadIdx.x;
    u16* dst = out + ((size_t)Nt * KT + Kt) * 8192;
#pragma unroll
    for (int i = 0; i < 4; ++i) {
        int c    = i * 256 + t;
        int ell  = c & 63;
        int nrow = Nt * 128 + (c >> 7) * 16 + (ell & 15);
        int kcol = Kt * 64 + (((c >> 6) & 1) * 4 + (ell >> 4)) * 8;
        alignas(16) u16 o[8];
#pragma unroll
        for (int q = 0; q < 8; ++q)
            o[q] = f2bf(W[(size_t)(kcol + q) * Wstride + colOff + nrow]);
        *(short8*)(dst + c * 8) = *(const short8*)o;
    }
}

// ---------------------------------------------------------------------------
// causal depthwise conv (taps=4): XP row-major bf16 -> XCp PACKED bf16.
// block per (k-tile, m-tile); writes are fully linear per tile.
// ---------------------------------------------------------------------------
__global__ __launch_bounds__(256)
void conv_kernel(const u16* __restrict__ XP, const float* __restrict__ conv_w,
                 const float* __restrict__ conv_b, u16* __restrict__ XCp)
{
    const int Kt = blockIdx.x;   // 0..31
    const int Mt = blockIdx.y;   // 0..127
    const int t  = threadIdx.x;
    u16* dst = XCp + ((size_t)Mt * 32 + Kt) * 8192;
#pragma unroll
    for (int i = 0; i < 4; ++i) {
        int c   = i * 256 + t;
        int ell = c & 63;
        int mr  = (c >> 7) * 16 + (ell & 15);
        int e   = Kt * 64 + (((c >> 6) & 1) * 4 + (ell >> 4)) * 8;
        int m   = Mt * 128 + mr;
        int l   = m & (SEQ - 1);
        float acc[8];
        {
            float4 c0 = *(const float4*)&conv_b[e];
            float4 c1 = *(const float4*)&conv_b[e + 4];
            acc[0] = c0.x; acc[1] = c0.y; acc[2] = c0.z; acc[3] = c0.w;
            acc[4] = c1.x; acc[5] = c1.y; acc[6] = c1.z; acc[7] = c1.w;
        }
#pragma unroll
        for (int k = 0; k < 4; ++k) {
            if (l - 3 + k >= 0) {
                const short8 xv = *(const short8*)&XP[(size_t)(m - 3 + k) * E_DIM + e];
#pragma unroll
                for (int j = 0; j < 8; ++j)
                    acc[j] += bf2f((u16)xv[j]) * conv_w[(size_t)(e + j) * 4 + k];
            }
        }
        alignas(16) u16 o[8];
#pragma unroll
        for (int j = 0; j < 8; ++j) o[j] = f2bf(acc[j]);
        *(short8*)(dst + c * 8) = *(const short8*)o;
    }
}

// ---------------------------------------------------------------------------
// U[m,s] = sum_e XCp[m,e] * A[e,s]  (fp32 acc; reads packed XCp)
// ---------------------------------------------------------------------------
__global__ __launch_bounds__(256)
void u_kernel(const u16* __restrict__ XCp, const float* __restrict__ Amat,
              float* __restrict__ U)
{
    __shared__ float part[(256 + 16) * HC_STR];
    const int m = blockIdx.x, t = threadIdx.x;
    const int Mt = m >> 7, mr = m & 127;
    const int Kt = t >> 3, c16 = t & 7;
    const int e0 = Kt * 64 + c16 * 8;
    const int c  = (mr >> 4) * 128 + (c16 >> 2) * 64 + (c16 & 3) * 16 + (mr & 15);
    const short8 xv = *(const short8*)&XCp[((size_t)Mt * 32 + Kt) * 8192 + (size_t)c * 8];

    float acc[16];
#pragma unroll
    for (int s = 0; s < 16; ++s) acc[s] = 0.f;
#pragma unroll
    for (int q = 0; q < 8; ++q) {
        float xq = bf2f((u16)xv[q]);
        const float4* ar = (const float4*)&Amat[(size_t)(e0 + q) * D_STATE];
#pragma unroll
        for (int s4 = 0; s4 < 4; ++s4) {
            float4 a = ar[s4];
            acc[s4 * 4 + 0] += xq * a.x; acc[s4 * 4 + 1] += xq * a.y;
            acc[s4 * 4 + 2] += xq * a.z; acc[s4 * 4 + 3] += xq * a.w;
        }
    }
#pragma unroll
    for (int s = 0; s < 16; ++s) part[t * HC_STR + s] = acc[s];
    __syncthreads();
    {
        int s = t & 15, grp = t >> 4;
        float sum = 0.f;
#pragma unroll
        for (int r = 0; r < 16; ++r) sum += part[(grp + r * 16) * HC_STR + s];
        part[(256 + grp) * HC_STR + s] = sum;
    }
    __syncthreads();
    if (t < 16) {
        float sum = 0.f;
#pragma unroll
        for (int g2 = 0; g2 < 16; ++g2) sum += part[(256 + g2) * HC_STR + t];
        U[(size_t)m * D_STATE + t] = sum;
    }
}

// ---------------------------------------------------------------------------
// sequential scan: h_l = tanh(U_l + h_{l-1}), 64 chains.
// Chunked by 8 with FULLY-UNROLLED static-index arrays (stay in VGPRs --
// R6's dynamic ring index spilled to scratch: 1413 us, 830 cyc/iter).
// Next chunk's 8 independent loads issue before this chunk's ~290-cycle
// dependent tanh chain, covering L2/L3 latency.
// ---------------------------------------------------------------------------
__global__ __launch_bounds__(64)
void scan_kernel(const float* __restrict__ U, float* __restrict__ H)
{
    const int t = threadIdx.x;
    const int b = t >> 4;
    const int s = t & 15;
    const float* u = U + (size_t)b * SEQ * D_STATE + s;
    float*       h = H + (size_t)b * SEQ * D_STATE + s;

    float cur[8], nxt[8];
#pragma unroll
    for (int j = 0; j < 8; ++j) cur[j] = u[(size_t)j * D_STATE];

    float hv = 0.f;
    for (int l0 = 0; l0 < SEQ; l0 += 8) {
        if (l0 + 8 < SEQ) {
#pragma unroll
            for (int j = 0; j < 8; ++j)
                nxt[j] = u[(size_t)(l0 + 8 + j) * D_STATE];
        }
#pragma unroll
        for (int j = 0; j < 8; ++j) {
            float ex = __expf(2.f * (cur[j] + hv));
            hv = 1.f - 2.f / (ex + 1.f);
            h[(size_t)(l0 + j) * D_STATE] = hv;
        }
#pragma unroll
        for (int j = 0; j < 8; ++j) cur[j] = nxt[j];
    }
}

// ---------------------------------------------------------------------------
extern "C" void kernel_launch(void* const* d_in, const int* in_sizes, int n_in,
                              void* d_out, int out_size, void* d_ws, size_t ws_size,
                              hipStream_t stream)
{
    const float* x      = (const float*)d_in[0];
    const float* W_in   = (const float*)d_in[1];
    const float* b_in   = (const float*)d_in[2];
    const float* conv_w = (const float*)d_in[3];
    const float* conv_b = (const float*)d_in[4];
    const float* Amat   = (const float*)d_in[5];
    const float* Cmat   = (const float*)d_in[6];
    const float* Dp     = (const float*)d_in[7];
    const float* W_out  = (const float*)d_in[8];
    const float* b_out  = (const float*)d_in[9];
    float* out = (float*)d_out;

    // workspace layout (115.3 MB total; 136 MB proven safe)
    char* ws = (char*)d_ws;
    u16*   xbp  = (u16*)(ws);                    // 33.55 MB packed x
    u16*   Wp0  = (u16*)(ws +  33554432);        //  4.19 MB packed W_in[:, :2048]^T
    u16*   Wp1  = (u16*)(ws +  37748736);        //  4.19 MB packed W_in[:, 2048:]^T
    u16*   Wp2  = (u16*)(ws +  41943040);        //  4.19 MB packed W_out^T
    u16*   XCp  = (u16*)(ws +  46137344);        // 67.11 MB packed x_conv
    float* U    = (float*)(ws + 113246208);      //  1.05 MB
    float* H    = (float*)(ws + 114294784);      //  1.05 MB
    u16*   XP   = (u16*)d_out;  // x_proj bf16 in d_out (67.1 MB), dead after conv

    // 1) pack inputs
    pack_x_kernel<<<dim3(16, 128), 256, 0, stream>>>(x, xbp);
    pack_w_kernel<<<dim3(16, 16), 256, 0, stream>>>(W_in, Wp0, 2 * E_DIM, 0, 16);
    pack_w_kernel<<<dim3(16, 16), 256, 0, stream>>>(W_in, Wp1, 2 * E_DIM, E_DIM, 16);
    pack_w_kernel<<<dim3(32, 8), 256, 0, stream>>>(W_out, Wp2, D_MODEL, 0, 32);

    // 2) XP = bf16(x @ W_in[:, :2048] + b_in)   (row-major, -> d_out)
    mfma_gemm<0><<<dim3(16, 128), 256, 0, stream>>>(
        xbp, Wp0, D_MODEL, E_DIM, b_in, XP, nullptr, nullptr, nullptr, nullptr, nullptr);

    // 3) XCp = packed bf16(causal_conv(XP) + conv_b)
    conv_kernel<<<dim3(32, 128), 256, 0, stream>>>(XP, conv_w, conv_b, XCp);

    // 4) U = XC @ A ; 5) scan -> H
    u_kernel<<<M_ROWS, 256, 0, stream>>>(XCp, Amat, U);
    scan_kernel<<<1, 64, 0, stream>>>(U, H);

    // 6) XCp <- sigmoid(x @ W_in[:, 2048:] + b_in[2048:]) * (H@C^T + Dp*XCp)
    mfma_gemm<1><<<dim3(16, 128), 256, 0, stream>>>(
        xbp, Wp1, D_MODEL, 0, b_in + E_DIM, nullptr, nullptr, H, Cmat, Dp, XCp);

    // 7) out = XC @ W_out + b_out   (fp32, row-major)
    mfma_gemm<2><<<dim3(8, 128), 256, 0, stream>>>(
        XCp, Wp2, E_DIM, D_MODEL, b_out, nullptr, out, nullptr, nullptr, nullptr, nullptr);
}

// Round 5
// 1096.807 us; speedup vs baseline: 1.2318x; 1.1634x over previous
//
#include <hip/hip_runtime.h>
#include <cstdint>
#include <cstddef>

#define D_MODEL 1024
#define D_STATE 16
#define E_DIM   2048
#define SEQ     4096
#define M_ROWS  16384

typedef unsigned short u16;
typedef unsigned int   u32;
typedef __attribute__((ext_vector_type(8))) short short8;   // 8 bf16 = 4 VGPRs
typedef __attribute__((ext_vector_type(4))) float f32x4;

__device__ __forceinline__ u16 f2bf(float f) {
    u32 u = __float_as_uint(f);
    u32 r = (u + 0x7fffu + ((u >> 16) & 1u)) >> 16;   // RNE
    return (u16)r;
}
__device__ __forceinline__ float bf2f(u16 h) {
    return __uint_as_float(((u32)h) << 16);
}

// ---------------------------------------------------------------------------
// PACKED TILE LAYOUT: every GEMM operand is stored as fragment-linear 128x64
// bf16 tiles (8192 u16). Chunk c (0..1023, 16 B each): msub=c>>7,
// step=(c>>6)&1, ell=c&63 -> row = msub*16+(ell&15),
// cols = (step*4 + (ell>>4))*8 .. +7.  A lane's MFMA fragment (sub, step) is
// the 16 contiguous bytes at tile_base + ((sub*2+step)*64 + lane)*8 u16 --
// so fragments are loaded DIRECTLY global->VGPR, fully coalesced (the wave
// reads a contiguous 1 KB per global_load_dwordx4).
// Tile (Mt, Kt) of an [M, K] operand lives at ((Mt*(K/64) + Kt) * 8192).
// ---------------------------------------------------------------------------
#define BM 128
#define BN 128
#define HC_STR 17   // padded float stride for epilogue H/C tiles

// packed elementwise offset for XCp (K-dim = E_DIM = 2048, 32 k-tiles)
__device__ __forceinline__ size_t xcp_off(int m, int n) {
    int Mt = m >> 7, mr = m & 127;
    int Kt = n >> 6, nt = n & 63;
    int c16 = nt >> 3;
    int c = (mr >> 4) * 128 + (c16 >> 2) * 64 + (c16 & 3) * 16 + (mr & 15);
    return ((size_t)Mt * 32 + Kt) * 8192 + (size_t)c * 8 + (nt & 7);
}

// ---------------------------------------------------------------------------
// MFMA GEMM on packed operands. C[M,N] = A[M,K] @ B[N,K]^T.
// 128x128 tile, BK=64, 4 waves (2x2 of 64x64), 4x4 16x16x32 MFMA per wave.
//
// R4: REGISTER-DIRECT K-LOOP (no LDS, no barriers, no global_load_lds).
// Occupancy was pinned at ~1 block/CU across all barrier-synced LDS
// structures (509/423/390 us, MfmaUtil 5-7%, ~1.3 KB/CU in flight). Each
// wave now streams its own fragments global->VGPR (packed layout =
// fragment-linear -> coalesced contiguous 1 KB per load), ping-ponging 2
// k-tiles of fragments in registers with static indexing. R4 verified:
// GEMMs dropped out of the top-5 dispatches.
//
// XCD swizzle: L%8 ~ XCD; XCD x owns m-strip, sweeps n within it.
// MODE 0: out bf16 row-major = acc + bias   (-> XP)
// MODE 1: gate: XCp <- sigmoid(acc+bias) * (H@C^T + Dp*XCp), packed in-place
// MODE 2: out fp32 row-major = acc + bias   (-> final out)
// ---------------------------------------------------------------------------
template <int MODE>
__global__ __launch_bounds__(256)
void mfma_gemm(const u16* __restrict__ Ag, const u16* __restrict__ Bg,
               int K, int Nst,
               const float* __restrict__ bias,
               u16* __restrict__ outb, float* __restrict__ outf,
               const float* __restrict__ Hm, const float* __restrict__ Cm,
               const float* __restrict__ Dp, u16* __restrict__ XCp)
{
    const int t     = threadIdx.x;
    const int lane  = t & 63;
    const int w     = t >> 6;
    const int col_l = lane & 15;
    const int quad  = lane >> 4;
    const int wm = (w & 1) * 64;
    const int wn = (w >> 1) * 64;

    // XCD-aware swizzle (block->XCD ~ L%8): XCD owns contiguous m-strip.
    const int L = blockIdx.y * gridDim.x + blockIdx.x;
    const int xcd = L & 7, g = L >> 3;
    const int ntile = g % gridDim.x;
    const int mtile = xcd * (gridDim.y >> 3) + g / gridDim.x;
    const int bm = mtile * BM;
    const int bn = ntile * BN;

    const int KT = K >> 6;
    // per-wave fragment base: frag (i, step) of k-tile kt lives at
    //   base + kt*8192 + (i*2+step)*512   (u16 units; 16 B per lane)
    const u16* aw = Ag + (size_t)mtile * KT * 8192 + (size_t)(w & 1) * 4096
                       + (size_t)lane * 8;
    const u16* bw = Bg + (size_t)ntile * KT * 8192 + (size_t)(w >> 1) * 4096
                       + (size_t)lane * 8;

    f32x4 acc[4][4] = {};

    // load the 8 fragments (4 A + 4 B) of one K=32 step into registers
    auto ldfrag = [&](short8* da, short8* db, size_t off, int step) {
#pragma unroll
        for (int i = 0; i < 4; ++i) {
            da[i] = *(const short8*)(aw + off + (size_t)((i * 2 + step) * 512));
            db[i] = *(const short8*)(bw + off + (size_t)((i * 2 + step) * 512));
        }
    };
    auto mfma16 = [&](short8* af, short8* bfr) {
#pragma unroll
        for (int i = 0; i < 4; ++i)
#pragma unroll
            for (int j = 0; j < 4; ++j)
                acc[i][j] = __builtin_amdgcn_mfma_f32_16x16x32_bf16(
                    af[i], bfr[j], acc[i][j], 0, 0, 0);
    };

    // register ping-pong: 4 fragment groups (2 k-tiles), static indexing only
    short8 A0[4], B0[4], A1[4], B1[4], A2[4], B2[4], A3[4], B3[4];
    size_t off = 0;
    ldfrag(A0, B0, off, 0);
    ldfrag(A1, B1, off, 1);
    for (int kt = 0; kt < KT; kt += 2) {
        // prefetch k-tile kt+1 while computing kt
        ldfrag(A2, B2, off + 8192, 0);
        ldfrag(A3, B3, off + 8192, 1);
        mfma16(A0, B0);
        mfma16(A1, B1);
        // prefetch k-tile kt+2 while computing kt+1
        if (kt + 2 < KT) {
            ldfrag(A0, B0, off + 16384, 0);
            ldfrag(A1, B1, off + 16384, 1);
        }
        mfma16(A2, B2);
        mfma16(A3, B3);
        off += 16384;
    }

    // C/D layout: col = lane&15, row = quad*4 + reg   [verified m89/m91]
    if (MODE == 0) {
#pragma unroll
        for (int j = 0; j < 4; ++j) {
            int n = bn + wn + j * 16 + col_l;
            float bv = bias[n];
#pragma unroll
            for (int i = 0; i < 4; ++i) {
                int mb = bm + wm + i * 16 + quad * 4;
#pragma unroll
                for (int p = 0; p < 4; ++p)
                    outb[(size_t)(mb + p) * Nst + n] = f2bf(acc[i][j][p] + bv);
            }
        }
    } else if (MODE == 1) {
        __shared__ float Hs[BM * HC_STR];
        __shared__ float Cs[BN * HC_STR];
        for (int idx = t; idx < BM * D_STATE; idx += 256)
            Hs[(idx >> 4) * HC_STR + (idx & 15)] =
                Hm[(size_t)(bm + (idx >> 4)) * D_STATE + (idx & 15)];
        for (int idx = t; idx < BN * D_STATE; idx += 256)
            Cs[(idx >> 4) * HC_STR + (idx & 15)] =
                Cm[(size_t)(bn + (idx >> 4)) * D_STATE + (idx & 15)];
        __syncthreads();
#pragma unroll
        for (int i = 0; i < 4; ++i) {
            int ml = wm + i * 16 + quad * 4;
#pragma unroll
            for (int p = 0; p < 4; ++p) {
                float hrow[D_STATE];
#pragma unroll
                for (int s = 0; s < D_STATE; ++s)
                    hrow[s] = Hs[(ml + p) * HC_STR + s];
#pragma unroll
                for (int j = 0; j < 4; ++j) {
                    int nl = wn + j * 16 + col_l;
                    int n = bn + nl;
                    float z = acc[i][j][p] + bias[n];
                    float sig = 1.f / (1.f + __expf(-z));
                    float dot = 0.f;
#pragma unroll
                    for (int s = 0; s < D_STATE; ++s)
                        dot += hrow[s] * Cs[nl * HC_STR + s];
                    // packed in-place RMW: read & write the SAME address
                    size_t offx = xcp_off(bm + ml + p, n);
                    float xc = bf2f(XCp[offx]);
                    XCp[offx] = f2bf(sig * (dot + Dp[n] * xc));
                }
            }
        }
    } else {
#pragma unroll
        for (int j = 0; j < 4; ++j) {
            int n = bn + wn + j * 16 + col_l;
            float bv = bias[n];
#pragma unroll
            for (int i = 0; i < 4; ++i) {
                int mb = bm + wm + i * 16 + quad * 4;
#pragma unroll
                for (int p = 0; p < 4; ++p)
                    outf[(size_t)(mb + p) * Nst + n] = acc[i][j][p] + bv;
            }
        }
    }
}

// ---------------------------------------------------------------------------
// pack x fp32 [16384,1024] -> packed bf16 tiles (K-dim 1024, 16 k-tiles)
// ---------------------------------------------------------------------------
__global__ __launch_bounds__(256)
void pack_x_kernel(const float* __restrict__ x, u16* __restrict__ xp)
{
    const int Kt = blockIdx.x;   // 0..15
    const int Mt = blockIdx.y;   // 0..127
    const int t  = threadIdx.x;
    u16* dst = xp + ((size_t)Mt * 16 + Kt) * 8192;
#pragma unroll
    for (int i = 0; i < 4; ++i) {
        int c   = i * 256 + t;
        int ell = c & 63;
        int row = Mt * 128 + (c >> 7) * 16 + (ell & 15);
        int col = Kt * 64 + (((c >> 6) & 1) * 4 + (ell >> 4)) * 8;
        const float4* src = (const float4*)&x[(size_t)row * D_MODEL + col];
        float4 a = src[0], b = src[1];
        alignas(16) u16 o[8] = {f2bf(a.x), f2bf(a.y), f2bf(a.z), f2bf(a.w),
                                f2bf(b.x), f2bf(b.y), f2bf(b.z), f2bf(b.w)};
        *(short8*)(dst + c * 8) = *(const short8*)o;
    }
}

// ---------------------------------------------------------------------------
// pack W^T: src W [K, Wstride] fp32 (cols colOff..colOff+Nt*128) -> packed
// bf16 tiles of B = W^T [N, K].
// ---------------------------------------------------------------------------
__global__ __launch_bounds__(256)
void pack_w_kernel(const float* __restrict__ W, u16* __restrict__ out,
                   int Wstride, int colOff, int KT)
{
    const int Kt = blockIdx.x;
    const int Nt = blockIdx.y;
    const int t  = threadIdx.x;
    u16* dst = out + ((size_t)Nt * KT + Kt) * 8192;
#pragma unroll
    for (int i = 0; i < 4; ++i) {
        int c    = i * 256 + t;
        int ell  = c & 63;
        int nrow = Nt * 128 + (c >> 7) * 16 + (ell & 15);
        int kcol = Kt * 64 + (((c >> 6) & 1) * 4 + (ell >> 4)) * 8;
        alignas(16) u16 o[8];
#pragma unroll
        for (int q = 0; q < 8; ++q)
            o[q] = f2bf(W[(size_t)(kcol + q) * Wstride + colOff + nrow]);
        *(short8*)(dst + c * 8) = *(const short8*)o;
    }
}

// ---------------------------------------------------------------------------
// causal depthwise conv (taps=4): XP row-major bf16 -> XCp PACKED bf16.
// block per (k-tile, m-tile); writes are fully linear per tile.
// ---------------------------------------------------------------------------
__global__ __launch_bounds__(256)
void conv_kernel(const u16* __restrict__ XP, const float* __restrict__ conv_w,
                 const float* __restrict__ conv_b, u16* __restrict__ XCp)
{
    const int Kt = blockIdx.x;   // 0..31
    const int Mt = blockIdx.y;   // 0..127
    const int t  = threadIdx.x;
    u16* dst = XCp + ((size_t)Mt * 32 + Kt) * 8192;
#pragma unroll
    for (int i = 0; i < 4; ++i) {
        int c   = i * 256 + t;
        int ell = c & 63;
        int mr  = (c >> 7) * 16 + (ell & 15);
        int e   = Kt * 64 + (((c >> 6) & 1) * 4 + (ell >> 4)) * 8;
        int m   = Mt * 128 + mr;
        int l   = m & (SEQ - 1);
        float acc[8];
        {
            float4 c0 = *(const float4*)&conv_b[e];
            float4 c1 = *(const float4*)&conv_b[e + 4];
            acc[0] = c0.x; acc[1] = c0.y; acc[2] = c0.z; acc[3] = c0.w;
            acc[4] = c1.x; acc[5] = c1.y; acc[6] = c1.z; acc[7] = c1.w;
        }
#pragma unroll
        for (int k = 0; k < 4; ++k) {
            if (l - 3 + k >= 0) {
                const short8 xv = *(const short8*)&XP[(size_t)(m - 3 + k) * E_DIM + e];
#pragma unroll
                for (int j = 0; j < 8; ++j)
                    acc[j] += bf2f((u16)xv[j]) * conv_w[(size_t)(e + j) * 4 + k];
            }
        }
        alignas(16) u16 o[8];
#pragma unroll
        for (int j = 0; j < 8; ++j) o[j] = f2bf(acc[j]);
        *(short8*)(dst + c * 8) = *(const short8*)o;
    }
}

// ---------------------------------------------------------------------------
// R5: U partials. Old u_kernel fetched 269 MB to read 67 MB (scattered 16 B
// per lane -> full line per fragment; 4x over-fetch, 325 us). Now: block per
// (Kt-pair kp, Mt); thread t owns row rr=t>>1, col-half z=t&1, and reads the
// 8 CONTIGUOUS chunks of its row in each packed tile (wave = 4x256 B
// contiguous segments per q-step -> full line utilization). Pair-reduce via
// one shfl_xor(1); partials Up[kp][m][s] summed by u_reduce_kernel.
// Deterministic (no atomics); no LDS.
// chunk c for (rr, z, q): c = (rr>>4)*128 + z*64 + q*16 + (rr&15)
//   -> row = rr, cols = (z*4+q)*8 .. +7   [packed-layout identities]
// ---------------------------------------------------------------------------
__global__ __launch_bounds__(256)
void u_part_kernel(const u16* __restrict__ XCp, const float* __restrict__ Amat,
                   float* __restrict__ Up)
{
    const int kp = blockIdx.x;   // 0..15 (K-tile pair)
    const int Mt = blockIdx.y;   // 0..127
    const int t  = threadIdx.x;
    const int rr = t >> 1;       // row within tile, 0..127
    const int z  = t & 1;        // col-half (step)
    const int msub = rr >> 4, r = rr & 15;

    float acc[16];
#pragma unroll
    for (int s = 0; s < 16; ++s) acc[s] = 0.f;

#pragma unroll
    for (int kk = 0; kk < 2; ++kk) {
        const int Kt = kp * 2 + kk;
        const u16* tile = XCp + ((size_t)Mt * 32 + Kt) * 8192;
#pragma unroll
        for (int q = 0; q < 4; ++q) {
            const int c = msub * 128 + z * 64 + q * 16 + r;
            const short8 xv = *(const short8*)(tile + (size_t)c * 8);
            const int e0 = Kt * 64 + (z * 4 + q) * 8;
#pragma unroll
            for (int j = 0; j < 8; ++j) {
                float xq = bf2f((u16)xv[j]);
                const float4* ar = (const float4*)&Amat[(size_t)(e0 + j) * D_STATE];
#pragma unroll
                for (int s4 = 0; s4 < 4; ++s4) {
                    float4 a = ar[s4];
                    acc[s4 * 4 + 0] += xq * a.x; acc[s4 * 4 + 1] += xq * a.y;
                    acc[s4 * 4 + 2] += xq * a.z; acc[s4 * 4 + 3] += xq * a.w;
                }
            }
        }
    }
    // combine the two col-halves (partner lane = t^1, same row)
#pragma unroll
    for (int s = 0; s < 16; ++s) acc[s] += __shfl_xor(acc[s], 1);

    if (z == 0) {
        const int m = Mt * 128 + rr;
        float4* dst = (float4*)&Up[((size_t)kp * M_ROWS + m) * D_STATE];
        dst[0] = make_float4(acc[0], acc[1], acc[2], acc[3]);
        dst[1] = make_float4(acc[4], acc[5], acc[6], acc[7]);
        dst[2] = make_float4(acc[8], acc[9], acc[10], acc[11]);
        dst[3] = make_float4(acc[12], acc[13], acc[14], acc[15]);
    }
}

// U[m,s] = sum_kp Up[kp][m][s]   (16 coalesced slices, float4-vectorized)
__global__ __launch_bounds__(256)
void u_reduce_kernel(const float* __restrict__ Up, float* __restrict__ U)
{
    const int idx = blockIdx.x * 256 + threadIdx.x;   // 65536 float4 elems
    const float4* src = (const float4*)Up;
    float4 s = src[idx];
#pragma unroll
    for (int kp = 1; kp < 16; ++kp) {
        float4 v = src[(size_t)kp * (M_ROWS * D_STATE / 4) + idx];
        s.x += v.x; s.y += v.y; s.z += v.z; s.w += v.w;
    }
    ((float4*)U)[idx] = s;
}

// ---------------------------------------------------------------------------
// sequential scan: h_l = tanh(U_l + h_{l-1}), 64 chains.
// Chunked by 8 with FULLY-UNROLLED static-index arrays (stay in VGPRs).
// Next chunk's 8 independent loads issue before this chunk's ~290-cycle
// dependent tanh chain, covering L2/L3 latency.
// ---------------------------------------------------------------------------
__global__ __launch_bounds__(64)
void scan_kernel(const float* __restrict__ U, float* __restrict__ H)
{
    const int t = threadIdx.x;
    const int b = t >> 4;
    const int s = t & 15;
    const float* u = U + (size_t)b * SEQ * D_STATE + s;
    float*       h = H + (size_t)b * SEQ * D_STATE + s;

    float cur[8], nxt[8];
#pragma unroll
    for (int j = 0; j < 8; ++j) cur[j] = u[(size_t)j * D_STATE];

    float hv = 0.f;
    for (int l0 = 0; l0 < SEQ; l0 += 8) {
        if (l0 + 8 < SEQ) {
#pragma unroll
            for (int j = 0; j < 8; ++j)
                nxt[j] = u[(size_t)(l0 + 8 + j) * D_STATE];
        }
#pragma unroll
        for (int j = 0; j < 8; ++j) {
            float ex = __expf(2.f * (cur[j] + hv));
            hv = 1.f - 2.f / (ex + 1.f);
            h[(size_t)(l0 + j) * D_STATE] = hv;
        }
#pragma unroll
        for (int j = 0; j < 8; ++j) cur[j] = nxt[j];
    }
}

// ---------------------------------------------------------------------------
extern "C" void kernel_launch(void* const* d_in, const int* in_sizes, int n_in,
                              void* d_out, int out_size, void* d_ws, size_t ws_size,
                              hipStream_t stream)
{
    const float* x      = (const float*)d_in[0];
    const float* W_in   = (const float*)d_in[1];
    const float* b_in   = (const float*)d_in[2];
    const float* conv_w = (const float*)d_in[3];
    const float* conv_b = (const float*)d_in[4];
    const float* Amat   = (const float*)d_in[5];
    const float* Cmat   = (const float*)d_in[6];
    const float* Dp     = (const float*)d_in[7];
    const float* W_out  = (const float*)d_in[8];
    const float* b_out  = (const float*)d_in[9];
    float* out = (float*)d_out;

    // workspace layout (132.1 MB total; 136 MB proven safe)
    char* ws = (char*)d_ws;
    u16*   xbp  = (u16*)(ws);                    // 33.55 MB packed x
    u16*   Wp0  = (u16*)(ws +  33554432);        //  4.19 MB packed W_in[:, :2048]^T
    u16*   Wp1  = (u16*)(ws +  37748736);        //  4.19 MB packed W_in[:, 2048:]^T
    u16*   Wp2  = (u16*)(ws +  41943040);        //  4.19 MB packed W_out^T
    u16*   XCp  = (u16*)(ws +  46137344);        // 67.11 MB packed x_conv
    float* U    = (float*)(ws + 113246208);      //  1.05 MB
    float* H    = (float*)(ws + 114294784);      //  1.05 MB
    float* Up   = (float*)(ws + 115343360);      // 16.78 MB U partials (16x)
    u16*   XP   = (u16*)d_out;  // x_proj bf16 in d_out (67.1 MB), dead after conv

    // 1) pack inputs
    pack_x_kernel<<<dim3(16, 128), 256, 0, stream>>>(x, xbp);
    pack_w_kernel<<<dim3(16, 16), 256, 0, stream>>>(W_in, Wp0, 2 * E_DIM, 0, 16);
    pack_w_kernel<<<dim3(16, 16), 256, 0, stream>>>(W_in, Wp1, 2 * E_DIM, E_DIM, 16);
    pack_w_kernel<<<dim3(32, 8), 256, 0, stream>>>(W_out, Wp2, D_MODEL, 0, 32);

    // 2) XP = bf16(x @ W_in[:, :2048] + b_in)   (row-major, -> d_out)
    mfma_gemm<0><<<dim3(16, 128), 256, 0, stream>>>(
        xbp, Wp0, D_MODEL, E_DIM, b_in, XP, nullptr, nullptr, nullptr, nullptr, nullptr);

    // 3) XCp = packed bf16(causal_conv(XP) + conv_b)
    conv_kernel<<<dim3(32, 128), 256, 0, stream>>>(XP, conv_w, conv_b, XCp);

    // 4) U = XC @ A  (partials + reduce); 5) scan -> H
    u_part_kernel<<<dim3(16, 128), 256, 0, stream>>>(XCp, Amat, Up);
    u_reduce_kernel<<<256, 256, 0, stream>>>(Up, U);
    scan_kernel<<<1, 64, 0, stream>>>(U, H);

    // 6) XCp <- sigmoid(x @ W_in[:, 2048:] + b_in[2048:]) * (H@C^T + Dp*XCp)
    mfma_gemm<1><<<dim3(16, 128), 256, 0, stream>>>(
        xbp, Wp1, D_MODEL, 0, b_in + E_DIM, nullptr, nullptr, H, Cmat, Dp, XCp);

    // 7) out = XC @ W_out + b_out   (fp32, row-major)
    mfma_gemm<2><<<dim3(8, 128), 256, 0, stream>>>(
        XCp, Wp2, E_DIM, D_MODEL, b_out, nullptr, out, nullptr, nullptr, nullptr, nullptr);
}

// Round 7
// 1087.396 us; speedup vs baseline: 1.2424x; 1.0087x over previous
//
#include <hip/hip_runtime.h>
#include <cstdint>
#include <cstddef>

#define D_MODEL 1024
#define D_STATE 16
#define E_DIM   2048
#define SEQ     4096
#define M_ROWS  16384

typedef unsigned short u16;
typedef unsigned int   u32;
typedef __attribute__((ext_vector_type(8))) short short8;   // 8 bf16 = 4 VGPRs
typedef __attribute__((ext_vector_type(4))) float f32x4;

__device__ __forceinline__ u16 f2bf(float f) {
    u32 u = __float_as_uint(f);
    u32 r = (u + 0x7fffu + ((u >> 16) & 1u)) >> 16;   // RNE
    return (u16)r;
}
__device__ __forceinline__ float bf2f(u16 h) {
    return __uint_as_float(((u32)h) << 16);
}

// ---------------------------------------------------------------------------
// PACKED TILE LAYOUT: every GEMM operand is stored as fragment-linear 128x64
// bf16 tiles (8192 u16). Chunk c (0..1023, 16 B each): msub=c>>7,
// step=(c>>6)&1, ell=c&63 -> row = msub*16+(ell&15),
// cols = (step*4 + (ell>>4))*8 .. +7.  A lane's MFMA fragment (sub, step) is
// the 16 contiguous bytes at tile_base + ((sub*2+step)*64 + lane)*8 u16 --
// so fragments are loaded DIRECTLY global->VGPR, fully coalesced (the wave
// reads a contiguous 1 KB per global_load_dwordx4).
// Tile (Mt, Kt) of an [M, K] operand lives at ((Mt*(K/64) + Kt) * 8192).
// ---------------------------------------------------------------------------
#define BM 128
#define BN 128
#define HC_STR 17   // padded float stride for epilogue H/C tiles

// packed elementwise offset for XCp (K-dim = E_DIM = 2048, 32 k-tiles)
__device__ __forceinline__ size_t xcp_off(int m, int n) {
    int Mt = m >> 7, mr = m & 127;
    int Kt = n >> 6, nt = n & 63;
    int c16 = nt >> 3;
    int c = (mr >> 4) * 128 + (c16 >> 2) * 64 + (c16 & 3) * 16 + (mr & 15);
    return ((size_t)Mt * 32 + Kt) * 8192 + (size_t)c * 8 + (nt & 7);
}

// ---------------------------------------------------------------------------
// MFMA GEMM on packed operands. C[M,N] = A[M,K] @ B[N,K]^T.
// 128x128 tile, BK=64, 4 waves (2x2 of 64x64), 4x4 16x16x32 MFMA per wave.
//
// R6: REGISTER-DIET K-LOOP. R5 counters: VGPR 176 -> floor(512/176) = 2
// waves/SIMD (observed ~1), MfmaUtil 9%, per-wave stall ~80% -- the 8-array
// ping-pong's 128 fragment VGPRs push us over the 512/170 residency cliff.
// TLP, not pipeline depth, hides latency here (R1-R3 established depth is
// dead); so: 4 fragment arrays (one k-tile: step0 + step1), refilled right
// after consumption. Frag regs 128 -> 64, target VGPR <= 112 -> 4-5
// waves/SIMD. L2-BW floor for this loop is ~57 us/GEMM; we run 5x above it
// on pure latency, so 4x wave interleave is the lever.
//
// XCD swizzle: L%8 ~ XCD; XCD x owns m-strip, sweeps n within it.
// MODE 0: out bf16 row-major = acc + bias   (-> XP)
// MODE 1: gate: XCp <- sigmoid(acc+bias) * (H@C^T + Dp*XCp), packed in-place
// MODE 2: out fp32 row-major = acc + bias   (-> final out)
// ---------------------------------------------------------------------------
template <int MODE>
__global__ __launch_bounds__(256)
void mfma_gemm(const u16* __restrict__ Ag, const u16* __restrict__ Bg,
               int K, int Nst,
               const float* __restrict__ bias,
               u16* __restrict__ outb, float* __restrict__ outf,
               const float* __restrict__ Hm, const float* __restrict__ Cm,
               const float* __restrict__ Dp, u16* __restrict__ XCp)
{
    const int t     = threadIdx.x;
    const int lane  = t & 63;
    const int w     = t >> 6;
    const int col_l = lane & 15;
    const int quad  = lane >> 4;
    const int wm = (w & 1) * 64;
    const int wn = (w >> 1) * 64;

    // XCD-aware swizzle (block->XCD ~ L%8): XCD owns contiguous m-strip.
    const int L = blockIdx.y * gridDim.x + blockIdx.x;
    const int xcd = L & 7, g = L >> 3;
    const int ntile = g % gridDim.x;
    const int mtile = xcd * (gridDim.y >> 3) + g / gridDim.x;
    const int bm = mtile * BM;
    const int bn = ntile * BN;

    const int KT = K >> 6;
    // per-wave fragment base: frag (i, step) of k-tile kt lives at
    //   base + kt*8192 + (i*2+step)*512   (u16 units; 16 B per lane)
    const u16* aw = Ag + (size_t)mtile * KT * 8192 + (size_t)(w & 1) * 4096
                       + (size_t)lane * 8;
    const u16* bw = Bg + (size_t)ntile * KT * 8192 + (size_t)(w >> 1) * 4096
                       + (size_t)lane * 8;

    f32x4 acc[4][4] = {};

    // load the 8 fragments (4 A + 4 B) of one K=32 step into registers
    auto ldfrag = [&](short8* da, short8* db, size_t off, int step) {
#pragma unroll
        for (int i = 0; i < 4; ++i) {
            da[i] = *(const short8*)(aw + off + (size_t)((i * 2 + step) * 512));
            db[i] = *(const short8*)(bw + off + (size_t)((i * 2 + step) * 512));
        }
    };
    auto mfma16 = [&](short8* af, short8* bfr) {
#pragma unroll
        for (int i = 0; i < 4; ++i)
#pragma unroll
            for (int j = 0; j < 4; ++j)
                acc[i][j] = __builtin_amdgcn_mfma_f32_16x16x32_bf16(
                    af[i], bfr[j], acc[i][j], 0, 0, 0);
    };

    // 1-k-tile register ping-pong: G0 = step0, G1 = step1; each refilled
    // with the next k-tile's step immediately after its MFMAs consume it.
    short8 A0[4], B0[4], A1[4], B1[4];
    size_t off = 0;
    ldfrag(A0, B0, 0, 0);
    ldfrag(A1, B1, 0, 1);
    for (int kt = 0; kt < KT; ++kt) {
        mfma16(A0, B0);                                   // consume step0
        if (kt + 1 < KT) ldfrag(A0, B0, off + 8192, 0);   // refill from kt+1
        mfma16(A1, B1);                                   // consume step1
        if (kt + 1 < KT) ldfrag(A1, B1, off + 8192, 1);
        off += 8192;
    }

    // C/D layout: col = lane&15, row = quad*4 + reg   [verified m89/m91]
    if (MODE == 0) {
#pragma unroll
        for (int j = 0; j < 4; ++j) {
            int n = bn + wn + j * 16 + col_l;
            float bv = bias[n];
#pragma unroll
            for (int i = 0; i < 4; ++i) {
                int mb = bm + wm + i * 16 + quad * 4;
#pragma unroll
                for (int p = 0; p < 4; ++p)
                    outb[(size_t)(mb + p) * Nst + n] = f2bf(acc[i][j][p] + bv);
            }
        }
    } else if (MODE == 1) {
        __shared__ float Hs[BM * HC_STR];
        __shared__ float Cs[BN * HC_STR];
        for (int idx = t; idx < BM * D_STATE; idx += 256)
            Hs[(idx >> 4) * HC_STR + (idx & 15)] =
                Hm[(size_t)(bm + (idx >> 4)) * D_STATE + (idx & 15)];
        for (int idx = t; idx < BN * D_STATE; idx += 256)
            Cs[(idx >> 4) * HC_STR + (idx & 15)] =
                Cm[(size_t)(bn + (idx >> 4)) * D_STATE + (idx & 15)];
        __syncthreads();
#pragma unroll
        for (int i = 0; i < 4; ++i) {
            int ml = wm + i * 16 + quad * 4;
#pragma unroll
            for (int p = 0; p < 4; ++p) {
                float hrow[D_STATE];
#pragma unroll
                for (int s = 0; s < D_STATE; ++s)
                    hrow[s] = Hs[(ml + p) * HC_STR + s];
#pragma unroll
                for (int j = 0; j < 4; ++j) {
                    int nl = wn + j * 16 + col_l;
                    int n = bn + nl;
                    float z = acc[i][j][p] + bias[n];
                    float sig = 1.f / (1.f + __expf(-z));
                    float dot = 0.f;
#pragma unroll
                    for (int s = 0; s < D_STATE; ++s)
                        dot += hrow[s] * Cs[nl * HC_STR + s];
                    // packed in-place RMW: read & write the SAME address
                    size_t offx = xcp_off(bm + ml + p, n);
                    float xc = bf2f(XCp[offx]);
                    XCp[offx] = f2bf(sig * (dot + Dp[n] * xc));
                }
            }
        }
    } else {
#pragma unroll
        for (int j = 0; j < 4; ++j) {
            int n = bn + wn + j * 16 + col_l;
            float bv = bias[n];
#pragma unroll
            for (int i = 0; i < 4; ++i) {
                int mb = bm + wm + i * 16 + quad * 4;
#pragma unroll
                for (int p = 0; p < 4; ++p)
                    outf[(size_t)(mb + p) * Nst + n] = acc[i][j][p] + bv;
            }
        }
    }
}

// ---------------------------------------------------------------------------
// pack x fp32 [16384,1024] -> packed bf16 tiles (K-dim 1024, 16 k-tiles)
// ---------------------------------------------------------------------------
__global__ __launch_bounds__(256)
void pack_x_kernel(const float* __restrict__ x, u16* __restrict__ xp)
{
    const int Kt = blockIdx.x;   // 0..15
    const int Mt = blockIdx.y;   // 0..127
    const int t  = threadIdx.x;
    u16* dst = xp + ((size_t)Mt * 16 + Kt) * 8192;
#pragma unroll
    for (int i = 0; i < 4; ++i) {
        int c   = i * 256 + t;
        int ell = c & 63;
        int row = Mt * 128 + (c >> 7) * 16 + (ell & 15);
        int col = Kt * 64 + (((c >> 6) & 1) * 4 + (ell >> 4)) * 8;
        const float4* src = (const float4*)&x[(size_t)row * D_MODEL + col];
        float4 a = src[0], b = src[1];
        alignas(16) u16 o[8] = {f2bf(a.x), f2bf(a.y), f2bf(a.z), f2bf(a.w),
                                f2bf(b.x), f2bf(b.y), f2bf(b.z), f2bf(b.w)};
        *(short8*)(dst + c * 8) = *(const short8*)o;
    }
}

// ---------------------------------------------------------------------------
// pack W^T: src W [K, Wstride] fp32 (cols colOff..colOff+Nt*128) -> packed
// bf16 tiles of B = W^T [N, K].
// ---------------------------------------------------------------------------
__global__ __launch_bounds__(256)
void pack_w_kernel(const float* __restrict__ W, u16* __restrict__ out,
                   int Wstride, int colOff, int KT)
{
    const int Kt = blockIdx.x;
    const int Nt = blockIdx.y;
    const int t  = threadIdx.x;
    u16* dst = out + ((size_t)Nt * KT + Kt) * 8192;
#pragma unroll
    for (int i = 0; i < 4; ++i) {
        int c    = i * 256 + t;
        int ell  = c & 63;
        int nrow = Nt * 128 + (c >> 7) * 16 + (ell & 15);
        int kcol = Kt * 64 + (((c >> 6) & 1) * 4 + (ell >> 4)) * 8;
        alignas(16) u16 o[8];
#pragma unroll
        for (int q = 0; q < 8; ++q)
            o[q] = f2bf(W[(size_t)(kcol + q) * Wstride + colOff + nrow]);
        *(short8*)(dst + c * 8) = *(const short8*)o;
    }
}

// ---------------------------------------------------------------------------
// causal depthwise conv (taps=4): XP row-major bf16 -> XCp PACKED bf16.
// block per (k-tile, m-tile); writes are fully linear per tile.
// ---------------------------------------------------------------------------
__global__ __launch_bounds__(256)
void conv_kernel(const u16* __restrict__ XP, const float* __restrict__ conv_w,
                 const float* __restrict__ conv_b, u16* __restrict__ XCp)
{
    const int Kt = blockIdx.x;   // 0..31
    const int Mt = blockIdx.y;   // 0..127
    const int t  = threadIdx.x;
    u16* dst = XCp + ((size_t)Mt * 32 + Kt) * 8192;
#pragma unroll
    for (int i = 0; i < 4; ++i) {
        int c   = i * 256 + t;
        int ell = c & 63;
        int mr  = (c >> 7) * 16 + (ell & 15);
        int e   = Kt * 64 + (((c >> 6) & 1) * 4 + (ell >> 4)) * 8;
        int m   = Mt * 128 + mr;
        int l   = m & (SEQ - 1);
        float acc[8];
        {
            float4 c0 = *(const float4*)&conv_b[e];
            float4 c1 = *(const float4*)&conv_b[e + 4];
            acc[0] = c0.x; acc[1] = c0.y; acc[2] = c0.z; acc[3] = c0.w;
            acc[4] = c1.x; acc[5] = c1.y; acc[6] = c1.z; acc[7] = c1.w;
        }
#pragma unroll
        for (int k = 0; k < 4; ++k) {
            if (l - 3 + k >= 0) {
                const short8 xv = *(const short8*)&XP[(size_t)(m - 3 + k) * E_DIM + e];
#pragma unroll
                for (int j = 0; j < 8; ++j)
                    acc[j] += bf2f((u16)xv[j]) * conv_w[(size_t)(e + j) * 4 + k];
            }
        }
        alignas(16) u16 o[8];
#pragma unroll
        for (int j = 0; j < 8; ++j) o[j] = f2bf(acc[j]);
        *(short8*)(dst + c * 8) = *(const short8*)o;
    }
}

// ---------------------------------------------------------------------------
// R5: U partials. block per (Kt-pair kp, Mt); thread t owns row rr=t>>1,
// col-half z=t&1, reads the 8 CONTIGUOUS chunks of its row in each packed
// tile (wave = 4x256 B contiguous segments per q-step -> full line
// utilization). Pair-reduce via one shfl_xor(1); partials Up[kp][m][s]
// summed by u_reduce_kernel. Deterministic; no LDS.
// chunk c for (rr, z, q): c = (rr>>4)*128 + z*64 + q*16 + (rr&15)
//   -> row = rr, cols = (z*4+q)*8 .. +7   [packed-layout identities]
// ---------------------------------------------------------------------------
__global__ __launch_bounds__(256)
void u_part_kernel(const u16* __restrict__ XCp, const float* __restrict__ Amat,
                   float* __restrict__ Up)
{
    const int kp = blockIdx.x;   // 0..15 (K-tile pair)
    const int Mt = blockIdx.y;   // 0..127
    const int t  = threadIdx.x;
    const int rr = t >> 1;       // row within tile, 0..127
    const int z  = t & 1;        // col-half (step)
    const int msub = rr >> 4, r = rr & 15;

    float acc[16];
#pragma unroll
    for (int s = 0; s < 16; ++s) acc[s] = 0.f;

#pragma unroll
    for (int kk = 0; kk < 2; ++kk) {
        const int Kt = kp * 2 + kk;
        const u16* tile = XCp + ((size_t)Mt * 32 + Kt) * 8192;
#pragma unroll
        for (int q = 0; q < 4; ++q) {
            const int c = msub * 128 + z * 64 + q * 16 + r;
            const short8 xv = *(const short8*)(tile + (size_t)c * 8);
            const int e0 = Kt * 64 + (z * 4 + q) * 8;
#pragma unroll
            for (int j = 0; j < 8; ++j) {
                float xq = bf2f((u16)xv[j]);
                const float4* ar = (const float4*)&Amat[(size_t)(e0 + j) * D_STATE];
#pragma unroll
                for (int s4 = 0; s4 < 4; ++s4) {
                    float4 a = ar[s4];
                    acc[s4 * 4 + 0] += xq * a.x; acc[s4 * 4 + 1] += xq * a.y;
                    acc[s4 * 4 + 2] += xq * a.z; acc[s4 * 4 + 3] += xq * a.w;
                }
            }
        }
    }
    // combine the two col-halves (partner lane = t^1, same row)
#pragma unroll
    for (int s = 0; s < 16; ++s) acc[s] += __shfl_xor(acc[s], 1);

    if (z == 0) {
        const int m = Mt * 128 + rr;
        float4* dst = (float4*)&Up[((size_t)kp * M_ROWS + m) * D_STATE];
        dst[0] = make_float4(acc[0], acc[1], acc[2], acc[3]);
        dst[1] = make_float4(acc[4], acc[5], acc[6], acc[7]);
        dst[2] = make_float4(acc[8], acc[9], acc[10], acc[11]);
        dst[3] = make_float4(acc[12], acc[13], acc[14], acc[15]);
    }
}

// U[m,s] = sum_kp Up[kp][m][s]   (16 coalesced slices, float4-vectorized)
__global__ __launch_bounds__(256)
void u_reduce_kernel(const float* __restrict__ Up, float* __restrict__ U)
{
    const int idx = blockIdx.x * 256 + threadIdx.x;   // 65536 float4 elems
    const float4* src = (const float4*)Up;
    float4 s = src[idx];
#pragma unroll
    for (int kp = 1; kp < 16; ++kp) {
        float4 v = src[(size_t)kp * (M_ROWS * D_STATE / 4) + idx];
        s.x += v.x; s.y += v.y; s.z += v.z; s.w += v.w;
    }
    ((float4*)U)[idx] = s;
}

// ---------------------------------------------------------------------------
// sequential scan: h_l = tanh(U_l + h_{l-1}), 64 chains.
// Chunked by 8 with FULLY-UNROLLED static-index arrays (stay in VGPRs).
// Next chunk's 8 independent loads issue before this chunk's ~290-cycle
// dependent tanh chain, covering L2/L3 latency.
// ---------------------------------------------------------------------------
__global__ __launch_bounds__(64)
void scan_kernel(const float* __restrict__ U, float* __restrict__ H)
{
    const int t = threadIdx.x;
    const int b = t >> 4;
    const int s = t & 15;
    const float* u = U + (size_t)b * SEQ * D_STATE + s;
    float*       h = H + (size_t)b * SEQ * D_STATE + s;

    float cur[8], nxt[8];
#pragma unroll
    for (int j = 0; j < 8; ++j) cur[j] = u[(size_t)j * D_STATE];

    float hv = 0.f;
    for (int l0 = 0; l0 < SEQ; l0 += 8) {
        if (l0 + 8 < SEQ) {
#pragma unroll
            for (int j = 0; j < 8; ++j)
                nxt[j] = u[(size_t)(l0 + 8 + j) * D_STATE];
        }
#pragma unroll
        for (int j = 0; j < 8; ++j) {
            float ex = __expf(2.f * (cur[j] + hv));
            hv = 1.f - 2.f / (ex + 1.f);
            h[(size_t)(l0 + j) * D_STATE] = hv;
        }
#pragma unroll
        for (int j = 0; j < 8; ++j) cur[j] = nxt[j];
    }
}

// ---------------------------------------------------------------------------
extern "C" void kernel_launch(void* const* d_in, const int* in_sizes, int n_in,
                              void* d_out, int out_size, void* d_ws, size_t ws_size,
                              hipStream_t stream)
{
    const float* x      = (const float*)d_in[0];
    const float* W_in   = (const float*)d_in[1];
    const float* b_in   = (const float*)d_in[2];
    const float* conv_w = (const float*)d_in[3];
    const float* conv_b = (const float*)d_in[4];
    const float* Amat   = (const float*)d_in[5];
    const float* Cmat   = (const float*)d_in[6];
    const float* Dp     = (const float*)d_in[7];
    const float* W_out  = (const float*)d_in[8];
    const float* b_out  = (const float*)d_in[9];
    float* out = (float*)d_out;

    // workspace layout (132.1 MB total; 136 MB proven safe)
    char* ws = (char*)d_ws;
    u16*   xbp  = (u16*)(ws);                    // 33.55 MB packed x
    u16*   Wp0  = (u16*)(ws +  33554432);        //  4.19 MB packed W_in[:, :2048]^T
    u16*   Wp1  = (u16*)(ws +  37748736);        //  4.19 MB packed W_in[:, 2048:]^T
    u16*   Wp2  = (u16*)(ws +  41943040);        //  4.19 MB packed W_out^T
    u16*   XCp  = (u16*)(ws +  46137344);        // 67.11 MB packed x_conv
    float* U    = (float*)(ws + 113246208);      //  1.05 MB
    float* H    = (float*)(ws + 114294784);      //  1.05 MB
    float* Up   = (float*)(ws + 115343360);      // 16.78 MB U partials (16x)
    u16*   XP   = (u16*)d_out;  // x_proj bf16 in d_out (67.1 MB), dead after conv

    // 1) pack inputs
    pack_x_kernel<<<dim3(16, 128), 256, 0, stream>>>(x, xbp);
    pack_w_kernel<<<dim3(16, 16), 256, 0, stream>>>(W_in, Wp0, 2 * E_DIM, 0, 16);
    pack_w_kernel<<<dim3(16, 16), 256, 0, stream>>>(W_in, Wp1, 2 * E_DIM, E_DIM, 16);
    pack_w_kernel<<<dim3(32, 8), 256, 0, stream>>>(W_out, Wp2, D_MODEL, 0, 32);

    // 2) XP = bf16(x @ W_in[:, :2048] + b_in)   (row-major, -> d_out)
    mfma_gemm<0><<<dim3(16, 128), 256, 0, stream>>>(
        xbp, Wp0, D_MODEL, E_DIM, b_in, XP, nullptr, nullptr, nullptr, nullptr, nullptr);

    // 3) XCp = packed bf16(causal_conv(XP) + conv_b)
    conv_kernel<<<dim3(32, 128), 256, 0, stream>>>(XP, conv_w, conv_b, XCp);

    // 4) U = XC @ A  (partials + reduce); 5) scan -> H
    u_part_kernel<<<dim3(16, 128), 256, 0, stream>>>(XCp, Amat, Up);
    u_reduce_kernel<<<256, 256, 0, stream>>>(Up, U);
    scan_kernel<<<1, 64, 0, stream>>>(U, H);

    // 6) XCp <- sigmoid(x @ W_in[:, 2048:] + b_in[2048:]) * (H@C^T + Dp*XCp)
    mfma_gemm<1><<<dim3(16, 128), 256, 0, stream>>>(
        xbp, Wp1, D_MODEL, 0, b_in + E_DIM, nullptr, nullptr, H, Cmat, Dp, XCp);

    // 7) out = XC @ W_out + b_out   (fp32, row-major)
    mfma_gemm<2><<<dim3(8, 128), 256, 0, stream>>>(
        XCp, Wp2, E_DIM, D_MODEL, b_out, nullptr, out, nullptr, nullptr, nullptr, nullptr);
}